// Round 5
// baseline (342.453 us; speedup 1.0000x reference)
//
#include <hip/hip_runtime.h>
#include <math.h>

// Net (per image b of 256):  x: (dh=256, wt=256), dh=d*16+h, wt=w*16+t
//  L1: w1 (17,17,9,9) pad4 -> (dh_o=64, wt=256) relu      [MFMA, 81 taps, K=256]
//  L2: w2 (7,7,7,7)  pad3 -> same, relu                   [MFMA, 49 taps, K=64]
//  L3: w3 (5,5,5,5)  pad2 -> relu                         [MFMA, 25 taps]
//  L4: w4 (3,3,3,3)  pad1 -> relu                         [MFMA,  9 taps]
//  L5: w5 (8,8)      -> sigmoid -> out (256,16,16)        [vector dot]
//
// R5: 512-thread blocks (8 waves, 2 waves/SIMD) to fix the 1-wave/SIMD
// latency stall seen in R4 (MfmaUtil 42%, Occupancy 11%). Each wave: m=2
// 16-wt tiles x n=64, 16 MFMA/tap. Structure otherwise = R4: per-(kw,kt)-tap
// banded GEMM, A from LDS (shifted rows, zero row for OOB), B fragment-ordered
// from global (L2/L1-resident), register-double-buffered 2-deep pipeline,
// mids in-place.

typedef short bf16x8 __attribute__((ext_vector_type(8)));
typedef float f32x4 __attribute__((ext_vector_type(4)));

#define XTS 72  // XT row stride in shorts (16B-aligned rows; start banks spread)

__device__ __forceinline__ unsigned short f2bf(float f) {
  unsigned int u = __float_as_uint(f);
  u += 0x7fffu + ((u >> 16) & 1u);  // RNE
  return (unsigned short)(u >> 16);
}

// ---------------- B-matrix precompute (all layers in one kernel) -------------
template <int KSZ, int PAD>
__device__ __forceinline__ void build_mid(const float* __restrict__ w,
                                          unsigned short* __restrict__ Bg, int gid) {
  const int lane = gid & 63;
  const int n_tile = (gid >> 6) & 3;
  const int chunk = (gid >> 8) & 1;
  const int tap = gid >> 9;
  const int kw = tap / KSZ, kt = tap - kw * KSZ;
  const int dh_o = n_tile * 16 + (lane & 15);
  const int d_o = dh_o >> 3, h_o = dh_o & 7;
  const int kbase = chunk * 32 + (lane >> 4) * 8;
  unsigned int pk[4];
#pragma unroll
  for (int p = 0; p < 4; ++p) {
    unsigned short half[2];
#pragma unroll
    for (int s = 0; s < 2; ++s) {
      const int k = kbase + p * 2 + s;
      const int d_i = k >> 3, h_i = k & 7;
      const int kd = d_i - d_o + PAD, kh = h_i - h_o + PAD;
      float v = 0.f;
      if (kd >= 0 && kd < KSZ && kh >= 0 && kh < KSZ)
        v = w[((kd * KSZ + kh) * KSZ + kw) * KSZ + kt];
      half[s] = f2bf(v);
    }
    pk[p] = (unsigned int)half[0] | ((unsigned int)half[1] << 16);
  }
  *(int4*)(Bg + (size_t)gid * 8) = make_int4(pk[0], pk[1], pk[2], pk[3]);
}

__global__ __launch_bounds__(256) void build_all(const float* __restrict__ w1,
                                                 const float* __restrict__ w2,
                                                 const float* __restrict__ w3,
                                                 const float* __restrict__ w4,
                                                 unsigned short* __restrict__ Bg1,
                                                 unsigned short* __restrict__ Bg2,
                                                 unsigned short* __restrict__ Bg3,
                                                 unsigned short* __restrict__ Bg4) {
  const int bid = blockIdx.x, tid = threadIdx.x;
  if (bid < 648) {  // L1: 81 taps * 8 chunks * 4 ntiles * 64 lanes
    const int gid = bid * 256 + tid;
    const int lane = gid & 63;
    const int n_tile = (gid >> 6) & 3;
    const int chunk = (gid >> 8) & 7;
    const int kwkt = gid >> 11;
    const int kw = kwkt / 9, kt = kwkt - kw * 9;
    const int dh_o = n_tile * 16 + (lane & 15);
    const int d_o = dh_o >> 3, h_o = dh_o & 7;
    const int kbase = chunk * 32 + (lane >> 4) * 8;
    unsigned int pk[4];
#pragma unroll
    for (int p = 0; p < 4; ++p) {
      unsigned short half[2];
#pragma unroll
      for (int s = 0; s < 2; ++s) {
        const int k = kbase + p * 2 + s;
        const int d_i = k >> 4, h_i = k & 15;
        const int kd = d_i - d_o + 4, kh = h_i - h_o + 4;
        float v = 0.f;
        if (kd >= 0 && kd < 17 && kh >= 0 && kh < 17)
          v = w1[((kd * 17 + kh) * 9 + kw) * 9 + kt];
        half[s] = f2bf(v);
      }
      pk[p] = (unsigned int)half[0] | ((unsigned int)half[1] << 16);
    }
    *(int4*)(Bg1 + (size_t)gid * 8) = make_int4(pk[0], pk[1], pk[2], pk[3]);
  } else if (bid < 746) {
    build_mid<7, 3>(w2, Bg2, (bid - 648) * 256 + tid);
  } else if (bid < 796) {
    build_mid<5, 2>(w3, Bg3, (bid - 746) * 256 + tid);
  } else {
    build_mid<3, 1>(w4, Bg4, (bid - 796) * 256 + tid);
  }
}

// ---------------- shared tap-loop pieces (m=2 tiles/wave) --------------------
__device__ __forceinline__ void mfma_block(const bf16x8 (&A)[4], const bf16x8 (&B)[8],
                                           f32x4 (&acc)[2][4]) {
#pragma unroll
  for (int c = 0; c < 2; ++c)
#pragma unroll
    for (int m = 0; m < 2; ++m)
#pragma unroll
      for (int n = 0; n < 4; ++n)
        acc[m][n] = __builtin_amdgcn_mfma_f32_16x16x32_bf16(A[c * 2 + m], B[c * 4 + n],
                                                            acc[m][n], 0, 0, 0);
}

template <int KSZ, int PAD, int CHTOT>
__device__ __forceinline__ void load_tap(const unsigned short* XT,
                                         const unsigned short* __restrict__ Bg,
                                         int chbase, int kwkt, int wave, int lane,
                                         int quad, int tl, bf16x8 (&A)[4], bf16x8 (&B)[8]) {
  const int kw = kwkt / KSZ, kt = kwkt - kw * KSZ;
  const int t_i = tl + kt - PAD;
  const bool tv = (unsigned)t_i < 16u;
  int ro[2];
#pragma unroll
  for (int m = 0; m < 2; ++m) {
    const int w_i = wave * 2 + m + kw - PAD;
    const bool v = tv && ((unsigned)w_i < 16u);
    const int row = v ? (w_i * 16 + t_i) : 256;  // row 256 = zeros
    ro[m] = row * XTS + quad * 8;
  }
#pragma unroll
  for (int c = 0; c < 2; ++c)
#pragma unroll
    for (int m = 0; m < 2; ++m)
      A[c * 2 + m] = *(const bf16x8*)&XT[ro[m] + c * 32];
#pragma unroll
  for (int c = 0; c < 2; ++c)
#pragma unroll
    for (int n = 0; n < 4; ++n)
      B[c * 4 + n] = *(const bf16x8*)(Bg + (((size_t)(kwkt * CHTOT + chbase + c) * 4 + n) << 9) +
                                      lane * 8);
}

#define TAP_PIPELINE(NT, LOADCALL)                    \
  {                                                   \
    bf16x8 A0[4], B0[8], A1[4], B1[8];                \
    LOADCALL(0, A0, B0);                              \
    int k2 = 0;                                       \
    while (true) {                                    \
      if (k2 + 1 < (NT)) LOADCALL(k2 + 1, A1, B1);    \
      mfma_block(A0, B0, acc);                        \
      if (++k2 >= (NT)) break;                        \
      if (k2 + 1 < (NT)) LOADCALL(k2 + 1, A0, B0);    \
      mfma_block(A1, B1, acc);                        \
      if (++k2 >= (NT)) break;                        \
    }                                                 \
  }

// ---------------- L1: K=256 in 4 LDS quarters --------------------------------
__global__ __launch_bounds__(512, 2) void conv_l1_mfma(const float* __restrict__ x,
                                                       const unsigned short* __restrict__ Bg,
                                                       const float* __restrict__ b1,
                                                       float* __restrict__ y) {
  __shared__ __align__(16) unsigned short XT[257 * XTS];
  const int b = blockIdx.x;
  const int tid = threadIdx.x;
  const int lane = tid & 63, wave = tid >> 6;
  const int quad = lane >> 4, tl = lane & 15;
  const float* xb = x + (size_t)b * 65536;
  f32x4 acc[2][4] = {};

  if (tid < 9) *(int4*)&XT[256 * XTS + tid * 8] = make_int4(0, 0, 0, 0);

  for (int kq = 0; kq < 4; ++kq) {
    __syncthreads();
#pragma unroll
    for (int it = 0; it < 4; ++it) {
      const int i = tid + it * 512;  // (dhp 0..31, wtq 0..63)
      const int dhp = i >> 6, wtq = i & 63;
      const float4 r0 = *(const float4*)(xb + (size_t)(kq * 64 + 2 * dhp) * 256 + wtq * 4);
      const float4 r1 = *(const float4*)(xb + (size_t)(kq * 64 + 2 * dhp + 1) * 256 + wtq * 4);
      const float a0[4] = {r0.x, r0.y, r0.z, r0.w};
      const float a1[4] = {r1.x, r1.y, r1.z, r1.w};
#pragma unroll
      for (int j = 0; j < 4; ++j) {
        const unsigned int p = (unsigned int)f2bf(a0[j]) | ((unsigned int)f2bf(a1[j]) << 16);
        *(unsigned int*)&XT[(wtq * 4 + j) * XTS + dhp * 2] = p;
      }
    }
    __syncthreads();
#define LT_L1(KK, AA, BB) load_tap<9, 4, 8>(XT, Bg, kq * 2, (KK), wave, lane, quad, tl, AA, BB)
    TAP_PIPELINE(81, LT_L1)
#undef LT_L1
  }

  const float bias = b1[0];
  float* yb = y + (size_t)b * 16384;
#pragma unroll
  for (int m = 0; m < 2; ++m)
#pragma unroll
    for (int n = 0; n < 4; ++n) {
      const int dh_o = n * 16 + tl;
      const int wt0 = wave * 32 + m * 16 + quad * 4;
      float4 v;
      v.x = fmaxf(acc[m][n][0] + bias, 0.f);
      v.y = fmaxf(acc[m][n][1] + bias, 0.f);
      v.z = fmaxf(acc[m][n][2] + bias, 0.f);
      v.w = fmaxf(acc[m][n][3] + bias, 0.f);
      *(float4*)&yb[(size_t)dh_o * 256 + wt0] = v;
    }
}

// ---------------- mid layers: K=64, in-place ---------------------------------
template <int KSZ, int PAD, int NT>
__global__ __launch_bounds__(512, 2) void conv_mid_mfma(float* __restrict__ y,
                                                        const unsigned short* __restrict__ Bg,
                                                        const float* __restrict__ bptr) {
  __shared__ __align__(16) unsigned short XT[257 * XTS];
  const int b = blockIdx.x;
  const int tid = threadIdx.x;
  const int lane = tid & 63, wave = tid >> 6;
  const int quad = lane >> 4, tl = lane & 15;
  float* yb = y + (size_t)b * 16384;
  f32x4 acc[2][4] = {};

  if (tid < 9) *(int4*)&XT[256 * XTS + tid * 8] = make_int4(0, 0, 0, 0);
#pragma unroll
  for (int it = 0; it < 4; ++it) {
    const int i = tid + it * 512;
    const int dhp = i >> 6, wtq = i & 63;
    const float4 r0 = *(const float4*)(yb + (size_t)(2 * dhp) * 256 + wtq * 4);
    const float4 r1 = *(const float4*)(yb + (size_t)(2 * dhp + 1) * 256 + wtq * 4);
    const float a0[4] = {r0.x, r0.y, r0.z, r0.w};
    const float a1[4] = {r1.x, r1.y, r1.z, r1.w};
#pragma unroll
    for (int j = 0; j < 4; ++j) {
      const unsigned int p = (unsigned int)f2bf(a0[j]) | ((unsigned int)f2bf(a1[j]) << 16);
      *(unsigned int*)&XT[(wtq * 4 + j) * XTS + dhp * 2] = p;
    }
  }
  __syncthreads();
#define LT_MID(KK, AA, BB) load_tap<KSZ, PAD, 2>(XT, Bg, 0, (KK), wave, lane, quad, tl, AA, BB)
  TAP_PIPELINE(NT, LT_MID)
#undef LT_MID

  const float bias = bptr[0];
#pragma unroll
  for (int m = 0; m < 2; ++m)
#pragma unroll
    for (int n = 0; n < 4; ++n) {
      const int dh_o = n * 16 + tl;
      const int wt0 = wave * 32 + m * 16 + quad * 4;
      float4 v;
      v.x = fmaxf(acc[m][n][0] + bias, 0.f);
      v.y = fmaxf(acc[m][n][1] + bias, 0.f);
      v.z = fmaxf(acc[m][n][2] + bias, 0.f);
      v.w = fmaxf(acc[m][n][3] + bias, 0.f);
      *(float4*)&yb[(size_t)dh_o * 256 + wt0] = v;
    }
}

// ---------------- L5 ---------------------------------------------------------
__global__ __launch_bounds__(256) void conv_l5(const float* __restrict__ x,
                                               const float* __restrict__ w5,
                                               const float* __restrict__ b5,
                                               float* __restrict__ out) {
  const int b = blockIdx.x;
  const int tid = threadIdx.x;
  const float* xb = x + (size_t)b * 16384 + tid;
  float s = b5[0];
#pragma unroll
  for (int k = 0; k < 64; ++k) s += xb[k * 256] * w5[k];
  out[(size_t)b * 256 + tid] = 1.f / (1.f + expf(-s));
}

extern "C" void kernel_launch(void* const* d_in, const int* in_sizes, int n_in,
                              void* d_out, int out_size, void* d_ws, size_t ws_size,
                              hipStream_t stream) {
  const float* corr = (const float*)d_in[0];
  const float* w1 = (const float*)d_in[1];
  const float* b1 = (const float*)d_in[2];
  const float* w2 = (const float*)d_in[3];
  const float* b2 = (const float*)d_in[4];
  const float* w3 = (const float*)d_in[5];
  const float* b3 = (const float*)d_in[6];
  const float* w4 = (const float*)d_in[7];
  const float* b4 = (const float*)d_in[8];
  const float* w5 = (const float*)d_in[9];
  const float* b5 = (const float*)d_in[10];

  float* A = (float*)d_ws;  // 16 MB activations, mids in-place
  unsigned short* Bg1 = (unsigned short*)((char*)d_ws + (16 << 20));
  unsigned short* Bg2 = Bg1 + (size_t)81 * 8 * 4 * 64 * 8;  // 1,327,104 shorts
  unsigned short* Bg3 = Bg2 + (size_t)49 * 2 * 4 * 64 * 8;  //   200,704
  unsigned short* Bg4 = Bg3 + (size_t)25 * 2 * 4 * 64 * 8;  //   102,400

  build_all<<<814, 256, 0, stream>>>(w1, w2, w3, w4, Bg1, Bg2, Bg3, Bg4);
  conv_l1_mfma<<<256, 512, 0, stream>>>(corr, Bg1, b1, A);
  conv_mid_mfma<7, 3, 49><<<256, 512, 0, stream>>>(A, Bg2, b2);
  conv_mid_mfma<5, 2, 25><<<256, 512, 0, stream>>>(A, Bg3, b3);
  conv_mid_mfma<3, 1, 9><<<256, 512, 0, stream>>>(A, Bg4, b4);
  conv_l5<<<256, 256, 0, stream>>>(A, w5, b5, (float*)d_out);
}